// Round 3
// baseline (6086.759 us; speedup 1.0000x reference)
//
#include <hip/hip_runtime.h>
#include <hip/hip_bf16.h>

// Problem: B=32, T=128, I=H=O=512, L=2, bidirectional GRU + FC head.
// ws layout (bytes):
//   proj (bf16): [2][128][32][1536]            = 12,582,912 elems * 2B = 25.17 MB
//   seq  (fp32): [2][128][32][512]             =  4,194,304 elems * 4B = 16.78 MB
//   slabs(fp32): [2l][2d][128jb][6144]         =  6,291,456 elems * 4B = 25.17 MB
// total 67.12 MB; barrier slots live in __device__ globals (zeroed by repack each launch)
#define PROJ_ELEMS 12582912
#define SEQ_ELEMS  4194304
#define SLAB_PER_BLK 6144

// Per-block barrier slots: g_slots[ld*128 + jb] holds the epoch (t+1) that block
// has finished. Arrival = ONE release store (no RMW serialization); detection =
// wave-parallel loads of all 128 slots in a single round trip. Monotonic, no reset.
__device__ unsigned g_slots[512];

// ---------------- proj GEMM: [8192 x 1536] = src @ [Wxh | Wxr] + bias -> bf16 ----------------
// grid (12, 64), block 256. 128x128 tile, 8x8 per-thread register tile.
__global__ __launch_bounds__(256)
void proj_kernel(const float* __restrict__ src,
                 const float* __restrict__ Wxh, const float* __restrict__ bxh,
                 const float* __restrict__ Wxr, const float* __restrict__ bxr,
                 __hip_bfloat16* __restrict__ proj, int layer)
{
    __shared__ float As[32][137];   // [k][row] transposed A tile
    __shared__ float Ws[32][132];   // [k][col]
    const int tid  = threadIdx.x;
    const int col0 = blockIdx.x * 128;
    const int row0 = blockIdx.y * 128;
    const int d    = row0 >> 12;              // rows 0..4095 = dir0, 4096..8191 = dir1
    const int ld   = layer * 2 + d;
    const int tx = tid & 15, ty = tid >> 4;

    const bool is_xr = (col0 >= 1024);
    const float* Wbase = is_xr ? (Wxr + (size_t)ld * 512 * 512 + (col0 - 1024))
                               : (Wxh + (size_t)ld * 512 * 1024 + col0);
    const int wstride = is_xr ? 512 : 1024;
    const float* bias = is_xr ? (bxr + ld * 512 + (col0 - 1024))
                              : (bxh + ld * 1024 + col0);

    float acc[8][8];
    #pragma unroll
    for (int i = 0; i < 8; i++)
        #pragma unroll
        for (int j = 0; j < 8; j++) acc[i][j] = 0.f;

    for (int k0 = 0; k0 < 512; k0 += 32) {
        #pragma unroll
        for (int v = 0; v < 4; v++) {
            int idx = tid + v * 256;
            int r   = idx >> 3;
            int c4  = (idx & 7) << 2;
            int gm  = row0 + r;
            int rr  = gm & 4095;
            int tt  = rr >> 5, bb = rr & 31;
            const float* p;
            if (layer == 0) {
                int ts = (gm >= 4096) ? (127 - tt) : tt;  // dir1 reads reversed time
                p = src + ((size_t)bb * 128 + ts) * 512 + (k0 + c4);
            } else {
                p = src + (((size_t)(gm >> 12) * 128 + tt) * 32 + bb) * 512 + (k0 + c4);
            }
            float4 vv = *(const float4*)p;
            As[c4 + 0][r] = vv.x; As[c4 + 1][r] = vv.y;
            As[c4 + 2][r] = vv.z; As[c4 + 3][r] = vv.w;
        }
        #pragma unroll
        for (int v = 0; v < 4; v++) {
            int idx = tid + v * 256;
            int kr  = idx >> 5;
            int c4  = (idx & 31) << 2;
            *(float4*)&Ws[kr][c4] = *(const float4*)(Wbase + (size_t)(k0 + kr) * wstride + c4);
        }
        __syncthreads();
        #pragma unroll
        for (int kk = 0; kk < 32; kk++) {
            float a[8], w[8];
            *(float4*)&a[0] = *(const float4*)&As[kk][ty * 8];
            *(float4*)&a[4] = *(const float4*)&As[kk][ty * 8 + 4];
            *(float4*)&w[0] = *(const float4*)&Ws[kk][tx * 8];
            *(float4*)&w[4] = *(const float4*)&Ws[kk][tx * 8 + 4];
            #pragma unroll
            for (int i = 0; i < 8; i++)
                #pragma unroll
                for (int j = 0; j < 8; j++)
                    acc[i][j] += a[i] * w[j];
        }
        __syncthreads();
    }
    #pragma unroll
    for (int i = 0; i < 8; i++) {
        int gm = row0 + ty * 8 + i;
        __hip_bfloat16* dst = proj + (size_t)gm * 1536 + col0 + tx * 8;
        #pragma unroll
        for (int j = 0; j < 8; j++)
            dst[j] = __float2bfloat16(acc[i][j] + bias[tx * 8 + j]);
    }
}

// ---------------- weight repack: per-(ld,jb) contiguous slab ----------------
// slab[(ld*128+jb)][idx], idx = (g*4+cg)*12 + e*4 + ki ; k = g*4+ki, j = jb*4+cg
// e: 0 = Whh z-col j, 1 = Whh r-col 512+j, 2 = Whr g-col j.
// Also zeroes the barrier slots (must run before the gru kernels).
__global__ __launch_bounds__(256)
void repack_kernel(const float* __restrict__ Whh, const float* __restrict__ Whr,
                   float* __restrict__ slabs)
{
    if (blockIdx.x == 0) {
        g_slots[threadIdx.x] = 0u;
        g_slots[threadIdx.x + 256] = 0u;
    }
    const int blk = blockIdx.x;           // 0..511 = ld*128 + jb
    const int ld = blk >> 7, jb = blk & 127;
    const float* WhhL = Whh + (size_t)ld * 512 * 1024;
    const float* WhrL = Whr + (size_t)ld * 512 * 512;
    float* out = slabs + (size_t)blk * SLAB_PER_BLK;
    for (int u = 0; u < 24; u++) {
        int idx = threadIdx.x + u * 256;  // 0..6143
        int rec = idx / 12, r3 = idx % 12;
        int g = rec >> 2, cg = rec & 3;
        int e = r3 >> 2, ki = r3 & 3;
        int k = g * 4 + ki, j = jb * 4 + cg;
        float v;
        if (e == 0)      v = WhhL[(size_t)k * 1024 + j];
        else if (e == 1) v = WhhL[(size_t)k * 1024 + 512 + j];
        else             v = WhrL[(size_t)k * 512 + j];
        out[idx] = v;
    }
}

// ---------------- fused GRU sequence: all 128 timesteps, one launch ----------------
// grid 256 = d*128 + jb (4 j-cols each), block 256 = (b = tid>>3, kh = bit2, cg = tid&3).
// Identical per-step math/layout to the proven step_kernel. Per-direction grid barrier:
// per-block slot stores (release) + one wave-parallel poll of all 128 slots. Replaces
// the single-counter fetch_add barrier whose 128 serialized RMWs cost ~13 us/step.
// 64 KB LDS -> 1 block/CU -> all 256 blocks co-resident (cooperative launch).
__global__ __launch_bounds__(256)
void gru_seq_kernel(const __hip_bfloat16* __restrict__ proj, float* __restrict__ seq,
                    const float* __restrict__ slabs,
                    const float* __restrict__ bhh, const float* __restrict__ bhr,
                    int layer)
{
    __shared__ __align__(16) float hs[32 * 512];  // h swizzled: [b][(g^(b&7))*4 + ki]
    const int tid = threadIdx.x;
    const int d   = blockIdx.x >> 7;
    const int jb  = blockIdx.x & 127;
    const int ld  = layer * 2 + d;
    const int cgi = tid & 3;
    const int kh  = (tid >> 2) & 1;
    const int b   = tid >> 3;
    const int j   = jb * 4 + cgi;
    const int sb  = b & 7;

    // loop invariants, loaded once per layer
    const float4* wrec = (const float4*)slabs + (size_t)(ld * 128 + jb) * 1536;
    const float bz = bhh[ld * 1024 + j];
    const float br = bhh[ld * 1024 + 512 + j];
    const float bg = bhr[ld * 512 + j];
    const float* hbase = seq + (size_t)(d * 128) * 32 * 512;
    const __hip_bfloat16* pbase = proj + ((size_t)(d * 128) * 32 + b) * 1536 + j;
    float* wout = seq + ((size_t)(d * 128) * 32 + b) * 512 + j;
    unsigned* slot_base = &g_slots[ld * 128];

    // software-pipelined proj load for t=0 (read-only data, no ordering constraints)
    __hip_bfloat16 rz = pbase[0], rr_ = pbase[512], rg = pbase[1024];

    for (int t = 0; t < 128; ++t) {
        if (t > 0) {
            // stage h(t-1) -> LDS with XOR-on-float4-slot swizzle (kills 8-way b-conflicts)
            const float* hsrc = hbase + (size_t)(t - 1) * 32 * 512;
            #pragma unroll
            for (int v = 0; v < 16; v++) {
                int id = tid + v * 256;           // float4 id 0..4095
                int bb = id >> 7, g = id & 127;
                float4 hv = *(const float4*)(hsrc + (size_t)id * 4);
                *(float4*)&hs[bb * 512 + ((g ^ (bb & 7)) << 2)] = hv;
            }
        }
        __syncthreads();

        float pz = __bfloat162float(rz);
        float pr = __bfloat162float(rr_);
        float pg = __bfloat162float(rg);

        float az = 0.f, ar = 0.f, ag = 0.f;
        float hv_self = 0.f;
        if (t > 0) {
            #pragma unroll 4
            for (int gg = 0; gg < 64; gg++) {
                int g = kh * 64 + gg;
                float4 h4 = *(const float4*)&hs[b * 512 + ((g ^ sb) << 2)];
                const float4* wp = wrec + (size_t)(g * 4 + cgi) * 3;
                float4 wz = wp[0], wr = wp[1], wg = wp[2];
                az += h4.x * wz.x + h4.y * wz.y + h4.z * wz.z + h4.w * wz.w;
                ar += h4.x * wr.x + h4.y * wr.y + h4.z * wr.z + h4.w * wr.w;
                ag += h4.x * wg.x + h4.y * wg.y + h4.z * wg.z + h4.w * wg.w;
            }
            // combine the two k-halves (lanes differ in bit 2)
            az += __shfl_xor(az, 4, 64);
            ar += __shfl_xor(ar, 4, 64);
            ag += __shfl_xor(ag, 4, 64);
            hv_self = hs[b * 512 + ((jb ^ sb) << 2) + cgi];   // g_self = j>>2 = jb
        }

        float z  = 1.f / (1.f + __expf(-(az + pz + bz)));
        float r  = 1.f / (1.f + __expf(-(ar + pr + br)));
        float gt = tanhf((ag + bg) * r + pg);
        float hn = z * hv_self + (1.f - z) * gt;
        if (kh == 0)
            wout[(size_t)t * 32 * 512] = hn;

        // ---- per-direction grid barrier ----
        if (t < 127) {
            __syncthreads();   // all threads' h stores drained (vmcnt 0) before arrival
            if (tid == 0)      // release: wbl2 + slot store (same semantics as R2, no RMW)
                __hip_atomic_store(slot_base + jb, (unsigned)(t + 1),
                                   __ATOMIC_RELEASE, __HIP_MEMORY_SCOPE_AGENT);

            // prefetch next-step proj while other blocks arrive (registers survive fences)
            const __hip_bfloat16* pn = pbase + (size_t)(t + 1) * 32 * 1536;
            rz = pn[0]; rr_ = pn[512]; rg = pn[1024];

            if (tid < 64) {
                const unsigned tgt = (unsigned)(t + 1);
                unsigned* s0 = slot_base + tid;
                unsigned* s1 = slot_base + 64 + tid;
                for (;;) {
                    unsigned a = __hip_atomic_load(s0, __ATOMIC_RELAXED,
                                                   __HIP_MEMORY_SCOPE_AGENT);
                    unsigned c = __hip_atomic_load(s1, __ATOMIC_RELAXED,
                                                   __HIP_MEMORY_SCOPE_AGENT);
                    if (__all(a >= tgt && c >= tgt)) break;
                    __builtin_amdgcn_s_sleep(1);
                }
            }
            __syncthreads();
            // acquire: invalidate stale cached h so reloads see other blocks' stores
            __builtin_amdgcn_fence(__ATOMIC_ACQUIRE, "agent");
        }
    }
}

// ---------------- final FC ----------------
__global__ __launch_bounds__(256)
void fc_kernel(const float* __restrict__ seq, const float* __restrict__ Wfc,
               const float* __restrict__ bfc, float* __restrict__ out)
{
    int idx = blockIdx.x * 256 + threadIdx.x;   // 0..16383
    int b = idx >> 9, o = idx & 511;
    const float* catf = seq + ((size_t)(0 * 128 + 127) * 32 + b) * 512;  // fwd, t=127
    const float* catr = seq + ((size_t)(1 * 128 + 0) * 32 + b) * 512;    // rev, t=0
    float acc = bfc[o];
    #pragma unroll 8
    for (int k = 0; k < 512; k++) acc += catf[k] * Wfc[(size_t)k * 512 + o];
    #pragma unroll 8
    for (int k = 0; k < 512; k++) acc += catr[k] * Wfc[(size_t)(512 + k) * 512 + o];
    out[(size_t)b * 512 + o] = acc;
}

extern "C" void kernel_launch(void* const* d_in, const int* in_sizes, int n_in,
                              void* d_out, int out_size, void* d_ws, size_t ws_size,
                              hipStream_t stream) {
    (void)in_sizes; (void)n_in; (void)out_size; (void)ws_size;
    const float* x   = (const float*)d_in[0];
    const float* Wxh = (const float*)d_in[1];
    const float* bxh = (const float*)d_in[2];
    const float* Whh = (const float*)d_in[3];
    const float* bhh = (const float*)d_in[4];
    const float* Wxr = (const float*)d_in[5];
    const float* bxr = (const float*)d_in[6];
    const float* Whr = (const float*)d_in[7];
    const float* bhr = (const float*)d_in[8];
    const float* Wfc = (const float*)d_in[9];
    const float* bfc = (const float*)d_in[10];
    float* out = (float*)d_out;

    char* base = (char*)d_ws;
    __hip_bfloat16* proj = (__hip_bfloat16*)base;
    float* seq   = (float*)(base + (size_t)PROJ_ELEMS * 2);
    float* slabs = seq + SEQ_ELEMS;

    repack_kernel<<<512, 256, 0, stream>>>(Whh, Whr, slabs);

    dim3 pgrid(12, 64);
    proj_kernel<<<pgrid, 256, 0, stream>>>(x, Wxh, bxh, Wxr, bxr, proj, 0);
    {
        int layer = 0;
        void* args[] = {(void*)&proj, (void*)&seq, (void*)&slabs,
                        (void*)&bhh, (void*)&bhr, (void*)&layer};
        hipLaunchCooperativeKernel((void*)gru_seq_kernel, dim3(256), dim3(256),
                                   args, 0, stream);
    }
    proj_kernel<<<pgrid, 256, 0, stream>>>(seq, Wxh, bxh, Wxr, bxr, proj, 1);
    {
        int layer = 1;
        void* args[] = {(void*)&proj, (void*)&seq, (void*)&slabs,
                        (void*)&bhh, (void*)&bhr, (void*)&layer};
        hipLaunchCooperativeKernel((void*)gru_seq_kernel, dim3(256), dim3(256),
                                   args, 0, stream);
    }
    fc_kernel<<<64, 256, 0, stream>>>(seq, Wfc, bfc, out);
}

// Round 4
// 3080.384 us; speedup vs baseline: 1.9760x; 1.9760x over previous
//
#include <hip/hip_runtime.h>
#include <hip/hip_bf16.h>

// Problem: B=32, T=128, I=H=O=512, L=2, bidirectional GRU + FC head.
// ws layout (bytes):
//   proj (bf16): [2][128][32][1536]            = 12,582,912 elems * 2B = 25.17 MB
//   seq  (fp32): [2][128][32][512]             =  4,194,304 elems * 4B = 16.78 MB
//   slabs(fp32): [2l][2d][128jb][6144]         =  6,291,456 elems * 4B = 25.17 MB
// total 67.12 MB; barrier slots live in __device__ globals (zeroed by repack each launch)
#define PROJ_ELEMS 12582912
#define SEQ_ELEMS  4194304
#define SLAB_PER_BLK 6144

typedef float f32x4 __attribute__((ext_vector_type(4)));

// Per-block barrier slots: g_slots[ld*128 + jb] holds the epoch (t+1) that block has
// finished. All slot traffic is RELAXED agent-scope (sc1) — no wbl2/inv cache
// maintenance. Monotonic, no reset; layers use disjoint ranges ([0,255] / [256,511]).
__device__ unsigned g_slots[512];

// ---------------- proj GEMM: [8192 x 1536] = src @ [Wxh | Wxr] + bias -> bf16 ----------------
// grid (12, 64), block 256. 128x128 tile, 8x8 per-thread register tile.
__global__ __launch_bounds__(256)
void proj_kernel(const float* __restrict__ src,
                 const float* __restrict__ Wxh, const float* __restrict__ bxh,
                 const float* __restrict__ Wxr, const float* __restrict__ bxr,
                 __hip_bfloat16* __restrict__ proj, int layer)
{
    __shared__ float As[32][137];   // [k][row] transposed A tile
    __shared__ float Ws[32][132];   // [k][col]
    const int tid  = threadIdx.x;
    const int col0 = blockIdx.x * 128;
    const int row0 = blockIdx.y * 128;
    const int d    = row0 >> 12;              // rows 0..4095 = dir0, 4096..8191 = dir1
    const int ld   = layer * 2 + d;
    const int tx = tid & 15, ty = tid >> 4;

    const bool is_xr = (col0 >= 1024);
    const float* Wbase = is_xr ? (Wxr + (size_t)ld * 512 * 512 + (col0 - 1024))
                               : (Wxh + (size_t)ld * 512 * 1024 + col0);
    const int wstride = is_xr ? 512 : 1024;
    const float* bias = is_xr ? (bxr + ld * 512 + (col0 - 1024))
                              : (bxh + ld * 1024 + col0);

    float acc[8][8];
    #pragma unroll
    for (int i = 0; i < 8; i++)
        #pragma unroll
        for (int j = 0; j < 8; j++) acc[i][j] = 0.f;

    for (int k0 = 0; k0 < 512; k0 += 32) {
        #pragma unroll
        for (int v = 0; v < 4; v++) {
            int idx = tid + v * 256;
            int r   = idx >> 3;
            int c4  = (idx & 7) << 2;
            int gm  = row0 + r;
            int rr  = gm & 4095;
            int tt  = rr >> 5, bb = rr & 31;
            const float* p;
            if (layer == 0) {
                int ts = (gm >= 4096) ? (127 - tt) : tt;  // dir1 reads reversed time
                p = src + ((size_t)bb * 128 + ts) * 512 + (k0 + c4);
            } else {
                p = src + (((size_t)(gm >> 12) * 128 + tt) * 32 + bb) * 512 + (k0 + c4);
            }
            float4 vv = *(const float4*)p;
            As[c4 + 0][r] = vv.x; As[c4 + 1][r] = vv.y;
            As[c4 + 2][r] = vv.z; As[c4 + 3][r] = vv.w;
        }
        #pragma unroll
        for (int v = 0; v < 4; v++) {
            int idx = tid + v * 256;
            int kr  = idx >> 5;
            int c4  = (idx & 31) << 2;
            *(float4*)&Ws[kr][c4] = *(const float4*)(Wbase + (size_t)(k0 + kr) * wstride + c4);
        }
        __syncthreads();
        #pragma unroll
        for (int kk = 0; kk < 32; kk++) {
            float a[8], w[8];
            *(float4*)&a[0] = *(const float4*)&As[kk][ty * 8];
            *(float4*)&a[4] = *(const float4*)&As[kk][ty * 8 + 4];
            *(float4*)&w[0] = *(const float4*)&Ws[kk][tx * 8];
            *(float4*)&w[4] = *(const float4*)&Ws[kk][tx * 8 + 4];
            #pragma unroll
            for (int i = 0; i < 8; i++)
                #pragma unroll
                for (int j = 0; j < 8; j++)
                    acc[i][j] += a[i] * w[j];
        }
        __syncthreads();
    }
    #pragma unroll
    for (int i = 0; i < 8; i++) {
        int gm = row0 + ty * 8 + i;
        __hip_bfloat16* dst = proj + (size_t)gm * 1536 + col0 + tx * 8;
        #pragma unroll
        for (int j = 0; j < 8; j++)
            dst[j] = __float2bfloat16(acc[i][j] + bias[tx * 8 + j]);
    }
}

// ---------------- weight repack: per-(ld,jb) contiguous slab ----------------
// slab[(ld*128+jb)][idx], idx = (g*4+cg)*12 + e*4 + ki ; k = g*4+ki, j = jb*4+cg
// e: 0 = Whh z-col j, 1 = Whh r-col 512+j, 2 = Whr g-col j.
// Also zeroes the barrier slots (must run before the gru kernels).
__global__ __launch_bounds__(256)
void repack_kernel(const float* __restrict__ Whh, const float* __restrict__ Whr,
                   float* __restrict__ slabs)
{
    if (blockIdx.x == 0) {
        g_slots[threadIdx.x] = 0u;
        g_slots[threadIdx.x + 256] = 0u;
    }
    const int blk = blockIdx.x;           // 0..511 = ld*128 + jb
    const int ld = blk >> 7, jb = blk & 127;
    const float* WhhL = Whh + (size_t)ld * 512 * 1024;
    const float* WhrL = Whr + (size_t)ld * 512 * 512;
    float* out = slabs + (size_t)blk * SLAB_PER_BLK;
    for (int u = 0; u < 24; u++) {
        int idx = threadIdx.x + u * 256;  // 0..6143
        int rec = idx / 12, r3 = idx % 12;
        int g = rec >> 2, cg = rec & 3;
        int e = r3 >> 2, ki = r3 & 3;
        int k = g * 4 + ki, j = jb * 4 + cg;
        float v;
        if (e == 0)      v = WhhL[(size_t)k * 1024 + j];
        else if (e == 1) v = WhhL[(size_t)k * 1024 + 512 + j];
        else             v = WhrL[(size_t)k * 512 + j];
        out[idx] = v;
    }
}

// ---------------- fused GRU sequence: all 128 timesteps, one launch ----------------
// grid 256 = d*128 + jb (4 j-cols each), block 256 = (b = tid>>3, kh = bit2, cg = tid&3).
// Coherence strategy: the ONLY cross-block data (h and barrier slots) moves via
// per-instruction agent-coherent (sc1) accesses through the LLC. No wbl2/buffer_inv
// fences -> slabs/proj/bias stay L1/L2-resident across all 128 steps. Ordering:
// __syncthreads() drains each wave's sc1 h-stores (vmcnt 0) before the slot store;
// readers' h-loads are sc1 so they can never hit stale L2 lines.
__global__ __launch_bounds__(256)
void gru_seq_kernel(const __hip_bfloat16* __restrict__ proj, float* __restrict__ seq,
                    const float* __restrict__ slabs,
                    const float* __restrict__ bhh, const float* __restrict__ bhr,
                    int layer)
{
    __shared__ __align__(16) float hs[32 * 512];  // h swizzled: [b][(g^(b&7))*4 + ki]
    const int tid = threadIdx.x;
    const int d   = blockIdx.x >> 7;
    const int jb  = blockIdx.x & 127;
    const int ld  = layer * 2 + d;
    const int cgi = tid & 3;
    const int kh  = (tid >> 2) & 1;
    const int b   = tid >> 3;
    const int j   = jb * 4 + cgi;
    const int sb  = b & 7;

    // loop invariants, loaded once per layer
    const float4* wrec = (const float4*)slabs + (size_t)(ld * 128 + jb) * 1536;
    const float bz = bhh[ld * 1024 + j];
    const float br = bhh[ld * 1024 + 512 + j];
    const float bg = bhr[ld * 512 + j];
    const float* hbase = seq + (size_t)(d * 128) * 32 * 512;
    const __hip_bfloat16* pbase = proj + ((size_t)(d * 128) * 32 + b) * 1536 + j;
    float* wout = seq + ((size_t)(d * 128) * 32 + b) * 512 + j;
    unsigned* slot_base = &g_slots[ld * 128];

    // software-pipelined proj load for t=0 (read-only data, normal cached loads)
    __hip_bfloat16 rz = pbase[0], rr_ = pbase[512], rg = pbase[1024];

    for (int t = 0; t < 128; ++t) {
        if (t > 0) {
            // stage h(t-1) -> LDS. Coherent (sc0 sc1) loads read the LLC directly,
            // bypassing any stale non-coherent L2 lines; then the proven
            // XOR-on-float4-slot swizzled LDS writes (kills 8-way b-conflicts).
            const float* hsrc = hbase + (size_t)(t - 1) * 32 * 512;
            f32x4 tmp[16];
            #pragma unroll
            for (int v = 0; v < 16; v++) {
                int id = tid + v * 256;           // float4 id 0..4095
                asm volatile("global_load_dwordx4 %0, %1, off sc0 sc1"
                             : "=v"(tmp[v])
                             : "v"((const void*)(hsrc + (size_t)id * 4)));
            }
            asm volatile("s_waitcnt vmcnt(0)" ::: "memory");
            #pragma unroll
            for (int v = 0; v < 16; v++) {
                int id = tid + v * 256;
                int bb = id >> 7, g = id & 127;
                *(f32x4*)&hs[bb * 512 + ((g ^ (bb & 7)) << 2)] = tmp[v];
            }
        }
        __syncthreads();

        float pz = __bfloat162float(rz);
        float pr = __bfloat162float(rr_);
        float pg = __bfloat162float(rg);

        float az = 0.f, ar = 0.f, ag = 0.f;
        float hv_self = 0.f;
        if (t > 0) {
            #pragma unroll 4
            for (int gg = 0; gg < 64; gg++) {
                int g = kh * 64 + gg;
                float4 h4 = *(const float4*)&hs[b * 512 + ((g ^ sb) << 2)];
                const float4* wp = wrec + (size_t)(g * 4 + cgi) * 3;
                float4 wz = wp[0], wr = wp[1], wg = wp[2];
                az += h4.x * wz.x + h4.y * wz.y + h4.z * wz.z + h4.w * wz.w;
                ar += h4.x * wr.x + h4.y * wr.y + h4.z * wr.z + h4.w * wr.w;
                ag += h4.x * wg.x + h4.y * wg.y + h4.z * wg.z + h4.w * wg.w;
            }
            // combine the two k-halves (lanes differ in bit 2)
            az += __shfl_xor(az, 4, 64);
            ar += __shfl_xor(ar, 4, 64);
            ag += __shfl_xor(ag, 4, 64);
            hv_self = hs[b * 512 + ((jb ^ sb) << 2) + cgi];   // g_self = j>>2 = jb
        }

        float z  = 1.f / (1.f + __expf(-(az + pz + bz)));
        float r  = 1.f / (1.f + __expf(-(ar + pr + br)));
        float gt = tanhf((ag + bg) * r + pg);
        float hn = z * hv_self + (1.f - z) * gt;
        if (kh == 0)   // coherent (sc1) write-through so other XCDs' sc1 loads see it
            __hip_atomic_store(wout + (size_t)t * 32 * 512, hn,
                               __ATOMIC_RELAXED, __HIP_MEMORY_SCOPE_AGENT);

        // ---- per-direction grid barrier (fence-free) ----
        if (t < 127) {
            __syncthreads();   // each wave drains vmcnt(0): all sc1 h-stores visible
            if (tid == 0)      // relaxed slot store (sc1) — no wbl2
                __hip_atomic_store(slot_base + jb, (unsigned)(t + 1),
                                   __ATOMIC_RELAXED, __HIP_MEMORY_SCOPE_AGENT);

            // prefetch next-step proj while other blocks arrive (normal cached loads)
            const __hip_bfloat16* pn = pbase + (size_t)(t + 1) * 32 * 1536;
            rz = pn[0]; rr_ = pn[512]; rg = pn[1024];

            if (tid < 64) {
                const unsigned tgt = (unsigned)(t + 1);
                unsigned* s0 = slot_base + tid;
                unsigned* s1 = slot_base + 64 + tid;
                for (;;) {
                    unsigned a = __hip_atomic_load(s0, __ATOMIC_RELAXED,
                                                   __HIP_MEMORY_SCOPE_AGENT);
                    unsigned c = __hip_atomic_load(s1, __ATOMIC_RELAXED,
                                                   __HIP_MEMORY_SCOPE_AGENT);
                    if (__all(a >= tgt && c >= tgt)) break;
                    __builtin_amdgcn_s_sleep(1);
                }
            }
            __syncthreads();   // no acquire fence: next step's h-loads are sc1
        }
    }
}

// ---------------- final FC ----------------
__global__ __launch_bounds__(256)
void fc_kernel(const float* __restrict__ seq, const float* __restrict__ Wfc,
               const float* __restrict__ bfc, float* __restrict__ out)
{
    int idx = blockIdx.x * 256 + threadIdx.x;   // 0..16383
    int b = idx >> 9, o = idx & 511;
    const float* catf = seq + ((size_t)(0 * 128 + 127) * 32 + b) * 512;  // fwd, t=127
    const float* catr = seq + ((size_t)(1 * 128 + 0) * 32 + b) * 512;    // rev, t=0
    float acc = bfc[o];
    #pragma unroll 8
    for (int k = 0; k < 512; k++) acc += catf[k] * Wfc[(size_t)k * 512 + o];
    #pragma unroll 8
    for (int k = 0; k < 512; k++) acc += catr[k] * Wfc[(size_t)(512 + k) * 512 + o];
    out[(size_t)b * 512 + o] = acc;
}

extern "C" void kernel_launch(void* const* d_in, const int* in_sizes, int n_in,
                              void* d_out, int out_size, void* d_ws, size_t ws_size,
                              hipStream_t stream) {
    (void)in_sizes; (void)n_in; (void)out_size; (void)ws_size;
    const float* x   = (const float*)d_in[0];
    const float* Wxh = (const float*)d_in[1];
    const float* bxh = (const float*)d_in[2];
    const float* Whh = (const float*)d_in[3];
    const float* bhh = (const float*)d_in[4];
    const float* Wxr = (const float*)d_in[5];
    const float* bxr = (const float*)d_in[6];
    const float* Whr = (const float*)d_in[7];
    const float* bhr = (const float*)d_in[8];
    const float* Wfc = (const float*)d_in[9];
    const float* bfc = (const float*)d_in[10];
    float* out = (float*)d_out;

    char* base = (char*)d_ws;
    __hip_bfloat16* proj = (__hip_bfloat16*)base;
    float* seq   = (float*)(base + (size_t)PROJ_ELEMS * 2);
    float* slabs = seq + SEQ_ELEMS;

    repack_kernel<<<512, 256, 0, stream>>>(Whh, Whr, slabs);

    dim3 pgrid(12, 64);
    proj_kernel<<<pgrid, 256, 0, stream>>>(x, Wxh, bxh, Wxr, bxr, proj, 0);
    {
        int layer = 0;
        void* args[] = {(void*)&proj, (void*)&seq, (void*)&slabs,
                        (void*)&bhh, (void*)&bhr, (void*)&layer};
        hipLaunchCooperativeKernel((void*)gru_seq_kernel, dim3(256), dim3(256),
                                   args, 0, stream);
    }
    proj_kernel<<<pgrid, 256, 0, stream>>>(seq, Wxh, bxh, Wxr, bxr, proj, 1);
    {
        int layer = 1;
        void* args[] = {(void*)&proj, (void*)&seq, (void*)&slabs,
                        (void*)&bhh, (void*)&bhr, (void*)&layer};
        hipLaunchCooperativeKernel((void*)gru_seq_kernel, dim3(256), dim3(256),
                                   args, 0, stream);
    }
    fc_kernel<<<64, 256, 0, stream>>>(seq, Wfc, bfc, out);
}

// Round 5
// 2910.540 us; speedup vs baseline: 2.0913x; 1.0584x over previous
//
#include <hip/hip_runtime.h>
#include <hip/hip_bf16.h>

// Problem: B=32, T=128, I=H=O=512, L=2, bidirectional GRU + FC head.
// ws layout (bytes):
//   proj (bf16): [2][128][32][1536]            = 12,582,912 elems * 2B = 25.17 MB
//   seq  (fp32): [2][128][32][512]             =  4,194,304 elems * 4B = 16.78 MB
//   slabs(fp32): [2l][2d][128jb][6144]         =  6,291,456 elems * 4B = 25.17 MB
// total 67.12 MB; barrier slots live in __device__ globals (zeroed by repack each launch)
#define PROJ_ELEMS 12582912
#define SEQ_ELEMS  4194304
#define SLAB_PER_BLK 6144

typedef float f32x4 __attribute__((ext_vector_type(4)));

// Per-block barrier slots: g_slots[ld*128 + jb] holds the epoch (t+1) that block has
// finished. All slot traffic is RELAXED agent-scope (sc1) — no wbl2/inv cache
// maintenance. Monotonic, no reset; layers use disjoint ranges ([0,255] / [256,511]).
__device__ unsigned g_slots[512];

// ---------------- proj GEMM: [8192 x 1536] = src @ [Wxh | Wxr] + bias -> bf16 ----------------
// grid (12, 64), block 256. 128x128 tile, 8x8 per-thread register tile.
__global__ __launch_bounds__(256)
void proj_kernel(const float* __restrict__ src,
                 const float* __restrict__ Wxh, const float* __restrict__ bxh,
                 const float* __restrict__ Wxr, const float* __restrict__ bxr,
                 __hip_bfloat16* __restrict__ proj, int layer)
{
    __shared__ float As[32][137];   // [k][row] transposed A tile
    __shared__ float Ws[32][132];   // [k][col]
    const int tid  = threadIdx.x;
    const int col0 = blockIdx.x * 128;
    const int row0 = blockIdx.y * 128;
    const int d    = row0 >> 12;              // rows 0..4095 = dir0, 4096..8191 = dir1
    const int ld   = layer * 2 + d;
    const int tx = tid & 15, ty = tid >> 4;

    const bool is_xr = (col0 >= 1024);
    const float* Wbase = is_xr ? (Wxr + (size_t)ld * 512 * 512 + (col0 - 1024))
                               : (Wxh + (size_t)ld * 512 * 1024 + col0);
    const int wstride = is_xr ? 512 : 1024;
    const float* bias = is_xr ? (bxr + ld * 512 + (col0 - 1024))
                              : (bxh + ld * 1024 + col0);

    float acc[8][8];
    #pragma unroll
    for (int i = 0; i < 8; i++)
        #pragma unroll
        for (int j = 0; j < 8; j++) acc[i][j] = 0.f;

    for (int k0 = 0; k0 < 512; k0 += 32) {
        #pragma unroll
        for (int v = 0; v < 4; v++) {
            int idx = tid + v * 256;
            int r   = idx >> 3;
            int c4  = (idx & 7) << 2;
            int gm  = row0 + r;
            int rr  = gm & 4095;
            int tt  = rr >> 5, bb = rr & 31;
            const float* p;
            if (layer == 0) {
                int ts = (gm >= 4096) ? (127 - tt) : tt;  // dir1 reads reversed time
                p = src + ((size_t)bb * 128 + ts) * 512 + (k0 + c4);
            } else {
                p = src + (((size_t)(gm >> 12) * 128 + tt) * 32 + bb) * 512 + (k0 + c4);
            }
            float4 vv = *(const float4*)p;
            As[c4 + 0][r] = vv.x; As[c4 + 1][r] = vv.y;
            As[c4 + 2][r] = vv.z; As[c4 + 3][r] = vv.w;
        }
        #pragma unroll
        for (int v = 0; v < 4; v++) {
            int idx = tid + v * 256;
            int kr  = idx >> 5;
            int c4  = (idx & 31) << 2;
            *(float4*)&Ws[kr][c4] = *(const float4*)(Wbase + (size_t)(k0 + kr) * wstride + c4);
        }
        __syncthreads();
        #pragma unroll
        for (int kk = 0; kk < 32; kk++) {
            float a[8], w[8];
            *(float4*)&a[0] = *(const float4*)&As[kk][ty * 8];
            *(float4*)&a[4] = *(const float4*)&As[kk][ty * 8 + 4];
            *(float4*)&w[0] = *(const float4*)&Ws[kk][tx * 8];
            *(float4*)&w[4] = *(const float4*)&Ws[kk][tx * 8 + 4];
            #pragma unroll
            for (int i = 0; i < 8; i++)
                #pragma unroll
                for (int j = 0; j < 8; j++)
                    acc[i][j] += a[i] * w[j];
        }
        __syncthreads();
    }
    #pragma unroll
    for (int i = 0; i < 8; i++) {
        int gm = row0 + ty * 8 + i;
        __hip_bfloat16* dst = proj + (size_t)gm * 1536 + col0 + tx * 8;
        #pragma unroll
        for (int j = 0; j < 8; j++)
            dst[j] = __float2bfloat16(acc[i][j] + bias[tx * 8 + j]);
    }
}

// ---------------- weight repack: per-(ld,jb) contiguous slab ----------------
// slab[(ld*128+jb)][idx], idx = (g*4+cg)*12 + e*4 + ki ; k = g*4+ki, j = jb*4+cg
// e: 0 = Whh z-col j, 1 = Whh r-col 512+j, 2 = Whr g-col j.
// Also zeroes the barrier slots (must run before the gru kernels).
__global__ __launch_bounds__(256)
void repack_kernel(const float* __restrict__ Whh, const float* __restrict__ Whr,
                   float* __restrict__ slabs)
{
    if (blockIdx.x == 0) {
        g_slots[threadIdx.x] = 0u;
        g_slots[threadIdx.x + 256] = 0u;
    }
    const int blk = blockIdx.x;           // 0..511 = ld*128 + jb
    const int ld = blk >> 7, jb = blk & 127;
    const float* WhhL = Whh + (size_t)ld * 512 * 1024;
    const float* WhrL = Whr + (size_t)ld * 512 * 512;
    float* out = slabs + (size_t)blk * SLAB_PER_BLK;
    for (int u = 0; u < 24; u++) {
        int idx = threadIdx.x + u * 256;  // 0..6143
        int rec = idx / 12, r3 = idx % 12;
        int g = rec >> 2, cg = rec & 3;
        int e = r3 >> 2, ki = r3 & 3;
        int k = g * 4 + ki, j = jb * 4 + cg;
        float v;
        if (e == 0)      v = WhhL[(size_t)k * 1024 + j];
        else if (e == 1) v = WhhL[(size_t)k * 1024 + 512 + j];
        else             v = WhrL[(size_t)k * 512 + j];
        out[idx] = v;
    }
}

// ---------------- fused GRU sequence: all 128 timesteps, one launch ----------------
// grid 256 = d*128 + jb (4 j-cols each), block 256 = (b = tid>>3, kh = bit2, cg = tid&3).
// Coherence: only cross-block data (h, barrier slots) moves via per-instruction
// agent-coherent (sc1) accesses through the LLC — no wbl2/inv fences, so per-CU
// caches stay warm. NEW in R5: the 24 KB weight slab is staged into LDS once per
// layer; the GEMV reads weights via ds_read_b128 (conflict-free record layout)
// instead of re-streaming 3 KB/thread/step from L1 — that L1 stream was the
// dominant term (~3-5 us of the 10.4 us/step). LDS: 64 KB hs + 24 KB wlds = 88 KB
// -> still 1 block/CU, cooperative co-residency unchanged.
__global__ __launch_bounds__(256)
void gru_seq_kernel(const __hip_bfloat16* __restrict__ proj, float* __restrict__ seq,
                    const float* __restrict__ slabs,
                    const float* __restrict__ bhh, const float* __restrict__ bhr,
                    int layer)
{
    __shared__ __align__(16) float hs[32 * 512];   // h swizzled: [b][(g^(b&7))*4 + ki]
    __shared__ __align__(16) float wlds[SLAB_PER_BLK];  // this block's weight slab
    const int tid = threadIdx.x;
    const int d   = blockIdx.x >> 7;
    const int jb  = blockIdx.x & 127;
    const int ld  = layer * 2 + d;
    const int cgi = tid & 3;
    const int kh  = (tid >> 2) & 1;
    const int b   = tid >> 3;
    const int j   = jb * 4 + cgi;
    const int sb  = b & 7;

    // loop invariants, loaded once per layer
    const f32x4* wrec = (const f32x4*)slabs + (size_t)(ld * 128 + jb) * 1536;
    const float bz = bhh[ld * 1024 + j];
    const float br = bhh[ld * 1024 + 512 + j];
    const float bg = bhr[ld * 512 + j];
    const float* hbase = seq + (size_t)(d * 128) * 32 * 512;
    const __hip_bfloat16* pbase = proj + ((size_t)(d * 128) * 32 + b) * 1536 + j;
    float* wout = seq + ((size_t)(d * 128) * 32 + b) * 512 + j;
    unsigned* slot_base = &g_slots[ld * 128];

    // one-time: slab -> LDS (6 float4 per thread); visible after the t=0 barrier
    #pragma unroll
    for (int u = 0; u < 6; u++)
        ((f32x4*)wlds)[tid + u * 256] = wrec[tid + u * 256];

    // software-pipelined proj load for t=0 (read-only data, normal cached loads)
    __hip_bfloat16 rz = pbase[0], rr_ = pbase[512], rg = pbase[1024];

    for (int t = 0; t < 128; ++t) {
        if (t > 0) {
            // stage h(t-1) -> LDS. Coherent (sc0 sc1) loads read the LLC directly,
            // bypassing any stale non-coherent L2 lines; then the proven
            // XOR-on-float4-slot swizzled LDS writes (kills 8-way b-conflicts).
            const float* hsrc = hbase + (size_t)(t - 1) * 32 * 512;
            f32x4 tmp[16];
            #pragma unroll
            for (int v = 0; v < 16; v++) {
                int id = tid + v * 256;           // float4 id 0..4095
                asm volatile("global_load_dwordx4 %0, %1, off sc0 sc1"
                             : "=v"(tmp[v])
                             : "v"((const void*)(hsrc + (size_t)id * 4)));
            }
            asm volatile("s_waitcnt vmcnt(0)" ::: "memory");
            #pragma unroll
            for (int v = 0; v < 16; v++) {
                int id = tid + v * 256;
                int bb = id >> 7, g = id & 127;
                *(f32x4*)&hs[bb * 512 + ((g ^ (bb & 7)) << 2)] = tmp[v];
            }
        }
        __syncthreads();

        float pz = __bfloat162float(rz);
        float pr = __bfloat162float(rr_);
        float pg = __bfloat162float(rg);

        float az = 0.f, ar = 0.f, ag = 0.f;
        float hv_self = 0.f;
        if (t > 0) {
            // weights from LDS: record (g*4+cg) = 3 float4 at float offset rec*12.
            // Wave bank pattern: cg spans disjoint bank quads, kh is a free 2-way.
            #pragma unroll 4
            for (int gg = 0; gg < 64; gg++) {
                int g = kh * 64 + gg;
                float4 h4 = *(const float4*)&hs[b * 512 + ((g ^ sb) << 2)];
                const f32x4* wp = (const f32x4*)wlds + (g * 4 + cgi) * 3;
                f32x4 wz = wp[0], wr = wp[1], wg = wp[2];
                az += h4.x * wz.x + h4.y * wz.y + h4.z * wz.z + h4.w * wz.w;
                ar += h4.x * wr.x + h4.y * wr.y + h4.z * wr.z + h4.w * wr.w;
                ag += h4.x * wg.x + h4.y * wg.y + h4.z * wg.z + h4.w * wg.w;
            }
            // combine the two k-halves (lanes differ in bit 2)
            az += __shfl_xor(az, 4, 64);
            ar += __shfl_xor(ar, 4, 64);
            ag += __shfl_xor(ag, 4, 64);
            hv_self = hs[b * 512 + ((jb ^ sb) << 2) + cgi];   // g_self = j>>2 = jb
        }

        float z  = 1.f / (1.f + __expf(-(az + pz + bz)));
        float r  = 1.f / (1.f + __expf(-(ar + pr + br)));
        float gt = tanhf((ag + bg) * r + pg);
        float hn = z * hv_self + (1.f - z) * gt;
        if (kh == 0)   // coherent (sc1) write-through so other XCDs' sc1 loads see it
            __hip_atomic_store(wout + (size_t)t * 32 * 512, hn,
                               __ATOMIC_RELAXED, __HIP_MEMORY_SCOPE_AGENT);

        // ---- per-direction grid barrier (fence-free) ----
        if (t < 127) {
            __syncthreads();   // each wave drains vmcnt(0): all sc1 h-stores visible
            if (tid == 0)      // relaxed slot store (sc1) — no wbl2
                __hip_atomic_store(slot_base + jb, (unsigned)(t + 1),
                                   __ATOMIC_RELAXED, __HIP_MEMORY_SCOPE_AGENT);

            // prefetch next-step proj while other blocks arrive (normal cached loads)
            const __hip_bfloat16* pn = pbase + (size_t)(t + 1) * 32 * 1536;
            rz = pn[0]; rr_ = pn[512]; rg = pn[1024];

            if (tid < 64) {
                const unsigned tgt = (unsigned)(t + 1);
                unsigned* s0 = slot_base + tid;
                unsigned* s1 = slot_base + 64 + tid;
                for (;;) {
                    unsigned a = __hip_atomic_load(s0, __ATOMIC_RELAXED,
                                                   __HIP_MEMORY_SCOPE_AGENT);
                    unsigned c = __hip_atomic_load(s1, __ATOMIC_RELAXED,
                                                   __HIP_MEMORY_SCOPE_AGENT);
                    if (__all(a >= tgt && c >= tgt)) break;
                    __builtin_amdgcn_s_sleep(1);
                }
            }
            __syncthreads();   // no acquire fence: next step's h-loads are sc1
        }
    }
}

// ---------------- final FC ----------------
__global__ __launch_bounds__(256)
void fc_kernel(const float* __restrict__ seq, const float* __restrict__ Wfc,
               const float* __restrict__ bfc, float* __restrict__ out)
{
    int idx = blockIdx.x * 256 + threadIdx.x;   // 0..16383
    int b = idx >> 9, o = idx & 511;
    const float* catf = seq + ((size_t)(0 * 128 + 127) * 32 + b) * 512;  // fwd, t=127
    const float* catr = seq + ((size_t)(1 * 128 + 0) * 32 + b) * 512;    // rev, t=0
    float acc = bfc[o];
    #pragma unroll 8
    for (int k = 0; k < 512; k++) acc += catf[k] * Wfc[(size_t)k * 512 + o];
    #pragma unroll 8
    for (int k = 0; k < 512; k++) acc += catr[k] * Wfc[(size_t)(512 + k) * 512 + o];
    out[(size_t)b * 512 + o] = acc;
}

extern "C" void kernel_launch(void* const* d_in, const int* in_sizes, int n_in,
                              void* d_out, int out_size, void* d_ws, size_t ws_size,
                              hipStream_t stream) {
    (void)in_sizes; (void)n_in; (void)out_size; (void)ws_size;
    const float* x   = (const float*)d_in[0];
    const float* Wxh = (const float*)d_in[1];
    const float* bxh = (const float*)d_in[2];
    const float* Whh = (const float*)d_in[3];
    const float* bhh = (const float*)d_in[4];
    const float* Wxr = (const float*)d_in[5];
    const float* bxr = (const float*)d_in[6];
    const float* Whr = (const float*)d_in[7];
    const float* bhr = (const float*)d_in[8];
    const float* Wfc = (const float*)d_in[9];
    const float* bfc = (const float*)d_in[10];
    float* out = (float*)d_out;

    char* base = (char*)d_ws;
    __hip_bfloat16* proj = (__hip_bfloat16*)base;
    float* seq   = (float*)(base + (size_t)PROJ_ELEMS * 2);
    float* slabs = seq + SEQ_ELEMS;

    repack_kernel<<<512, 256, 0, stream>>>(Whh, Whr, slabs);

    dim3 pgrid(12, 64);
    proj_kernel<<<pgrid, 256, 0, stream>>>(x, Wxh, bxh, Wxr, bxr, proj, 0);
    {
        int layer = 0;
        void* args[] = {(void*)&proj, (void*)&seq, (void*)&slabs,
                        (void*)&bhh, (void*)&bhr, (void*)&layer};
        hipLaunchCooperativeKernel((void*)gru_seq_kernel, dim3(256), dim3(256),
                                   args, 0, stream);
    }
    proj_kernel<<<pgrid, 256, 0, stream>>>(seq, Wxh, bxh, Wxr, bxr, proj, 1);
    {
        int layer = 1;
        void* args[] = {(void*)&proj, (void*)&seq, (void*)&slabs,
                        (void*)&bhh, (void*)&bhr, (void*)&layer};
        hipLaunchCooperativeKernel((void*)gru_seq_kernel, dim3(256), dim3(256),
                                   args, 0, stream);
    }
    fc_kernel<<<64, 256, 0, stream>>>(seq, Wfc, bfc, out);
}